// Round 18
// baseline (196.253 us; speedup 1.0000x reference)
//
#include <hip/hip_runtime.h>
#include <hip/hip_bf16.h>

#define NB 8
#define NQ 8192
#define MP 2048
#define CDW 256
#define CSK 128
#define CIN 384
#define COUT 256

typedef __bf16 bf16_t;
typedef bf16_t bf16x8 __attribute__((ext_vector_type(8)));
typedef float f32x4 __attribute__((ext_vector_type(4)));
typedef unsigned short ushort8 __attribute__((ext_vector_type(8)));

static __device__ __forceinline__ float bf2f(unsigned short u){
  union { unsigned int ui; float f; } v; v.ui = ((unsigned int)u) << 16; return v.f;
}
static __device__ __forceinline__ unsigned short f2bf(float f){
  union { float f; unsigned int u; } v; v.f = f;
  unsigned int u = v.u;
  return (unsigned short)((u + 0x7FFFu + ((u >> 16) & 1u)) >> 16);
}

// ---------------- weight conversion ----------------
__global__ void k_cvt_w(const float* __restrict__ W1, const float* __restrict__ W2,
                        unsigned short* __restrict__ W1b, unsigned short* __restrict__ W2b){
  int i = blockIdx.x * 256 + threadIdx.x;
  if (i < COUT*CIN) W1b[i] = f2bf(W1[i]);
  if (i < COUT*COUT) W2b[i] = f2bf(W2[i]);
}

// ---------------- Z = W1a * features_down : (B, M, 256) bf16, o-contiguous ----------------
__global__ __launch_bounds__(256) void k_z(const unsigned short* __restrict__ W1b,
    const float* __restrict__ fd, unsigned short* __restrict__ Z){
  __shared__ unsigned short Bl[64][264]; // [m][c], pad 8
  int b = blockIdx.y, m0 = blockIdx.x << 6;
  int t = threadIdx.x;
  {
    int m = t & 63, cs0 = t >> 6;
    for (int it = 0; it < 64; ++it){
      int c = cs0 + (it << 2);
      Bl[m][c] = f2bf(fd[((size_t)b*CDW + c)*MP + m0 + m]);
    }
  }
  __syncthreads();
  int l = t & 63, wv = t >> 6;
  int lr = l & 15, lg = l >> 4;
  int ob = wv << 6;
  f32x4 acc[4][4];
  #pragma unroll
  for (int i = 0; i < 4; ++i)
    #pragma unroll
    for (int j = 0; j < 4; ++j)
      acc[i][j] = (f32x4){0.f, 0.f, 0.f, 0.f};
  #pragma unroll 1
  for (int kt = 0; kt < 8; ++kt){
    int k0 = (kt << 5) + (lg << 3);
    bf16x8 af[4], bv[4];
    #pragma unroll
    for (int of = 0; of < 4; ++of)
      af[of] = *(const bf16x8*)(W1b + (size_t)(ob + (of<<4) + lr)*CIN + k0); // cols 0..255
    #pragma unroll
    for (int nf = 0; nf < 4; ++nf)
      bv[nf] = *(const bf16x8*)&Bl[(nf<<4) + lr][k0];
    #pragma unroll
    for (int of = 0; of < 4; ++of)
      #pragma unroll
      for (int nf = 0; nf < 4; ++nf)
        acc[of][nf] = __builtin_amdgcn_mfma_f32_16x16x32_bf16(af[of], bv[nf], acc[of][nf], 0, 0, 0);
  }
  #pragma unroll
  for (int of = 0; of < 4; ++of){
    int o = ob + (of<<4) + (lg<<2);
    #pragma unroll
    for (int nf = 0; nf < 4; ++nf){
      int m = m0 + (nf<<4) + lr;
      ushort4 pk;
      pk.x = f2bf(acc[of][nf][0]);
      pk.y = f2bf(acc[of][nf][1]);
      pk.z = f2bf(acc[of][nf][2]);
      pk.w = f2bf(acc[of][nf][3]);
      *(ushort4*)(Z + (((size_t)b*MP + m) << 8) + o) = pk;
    }
  }
}

// ---------------- 3-NN partial (M chunked, 512-pt chunks: skip x occupancy sweet spot) ----------------
#define CHUNKS 4
#define MC (MP/CHUNKS)

#define NN_SKIP(P)                                                           \
  asm volatile(                                                              \
      "v_fma_f32 %[s], %[qx], %[px], %[pw]\n\t"                              \
      "v_fma_f32 %[s], %[qy], %[py], %[s]\n\t"                               \
      "v_fma_f32 %[s], %[qz], %[pz], %[s]\n\t"                               \
      "v_cmp_gt_f32 vcc, %[s], %[s2]\n\t"                                    \
      "s_cbranch_vccz L_%=\n\t"                                              \
      "v_cmp_gt_f32 %[m1], %[s], %[s1]\n\t"                                  \
      "v_cmp_gt_f32 %[m0], %[s], %[s0]\n\t"                                  \
      "v_cndmask_b32 %[s2], %[s2], %[s], vcc\n\t"                            \
      "v_cndmask_b32 %[i2], %[i2], %[mi], vcc\n\t"                           \
      "v_cndmask_b32 %[s2], %[s2], %[s1], %[m1]\n\t"                         \
      "v_cndmask_b32 %[i2], %[i2], %[i1], %[m1]\n\t"                         \
      "v_cndmask_b32 %[s1], %[s1], %[s], %[m1]\n\t"                          \
      "v_cndmask_b32 %[i1], %[i1], %[mi], %[m1]\n\t"                         \
      "v_cndmask_b32 %[s1], %[s1], %[s0], %[m0]\n\t"                         \
      "v_cndmask_b32 %[i1], %[i1], %[i0], %[m0]\n\t"                         \
      "v_cndmask_b32 %[s0], %[s0], %[s], %[m0]\n\t"                          \
      "v_cndmask_b32 %[i0], %[i0], %[mi], %[m0]\n\t"                         \
      "L_%=:\n\t"                                                            \
      "v_add_u32 %[mi], 1, %[mi]\n\t"                                        \
      : [s]"=&v"(sv), [m0]"=&s"(mk0), [m1]"=&s"(mk1),                        \
        [s0]"+v"(s0), [s1]"+v"(s1), [s2]"+v"(s2),                            \
        [i0]"+v"(i0), [i1]"+v"(i1), [i2]"+v"(i2), [mi]"+v"(mi)               \
      : [qx]"v"(qx), [qy]"v"(qy), [qz]"v"(qz),                               \
        [px]"v"((P).x), [py]"v"((P).y), [pz]"v"((P).z), [pw]"v"((P).w)       \
      : "vcc")

__global__ __launch_bounds__(256, 2) void k_nn_part(const float* __restrict__ xu, const float* __restrict__ xd,
                                                    float* __restrict__ pd, int* __restrict__ pi){
  int b = blockIdx.z, ch = blockIdx.y, nt = blockIdx.x;
  int t = threadIdx.x;
  __shared__ float4 pts[MC];
  const float* xdb = xd + ((size_t)b*MP + (size_t)ch*MC)*3;
  for (int p = t; p < MC; p += 256){
    float x = xdb[p*3+0], y = xdb[p*3+1], z = xdb[p*3+2];
    pts[p] = make_float4(x, y, z, -0.5f*(x*x + y*y + z*z));
  }
  __syncthreads();
  int n = nt*256 + t;
  const float* q = xu + ((size_t)b*NQ + n)*3;
  float qx = q[0], qy = q[1], qz = q[2];
  float qs = qx*qx + qy*qy + qz*qz;
  float s0 = -3.4e38f, s1 = -3.4e38f, s2 = -3.4e38f;
  int i0 = 0, i1 = 0, i2 = 0, mi = 0;
  float sv;
  unsigned long long mk0, mk1;
  #pragma unroll 1
  for (int mb = 0; mb < MC; mb += 8){
    float4 P0 = pts[mb+0], P1 = pts[mb+1], P2 = pts[mb+2], P3 = pts[mb+3];
    float4 P4 = pts[mb+4], P5 = pts[mb+5], P6 = pts[mb+6], P7 = pts[mb+7];
    NN_SKIP(P0); NN_SKIP(P1); NN_SKIP(P2); NN_SKIP(P3);
    NN_SKIP(P4); NN_SKIP(P5); NN_SKIP(P6); NN_SKIP(P7);
  }
  int gb = ch*MC;
  size_t base = (((size_t)b*CHUNKS + ch)*NQ + n)*3;
  pd[base+0] = qs - 2.f*s0; pd[base+1] = qs - 2.f*s1; pd[base+2] = qs - 2.f*s2;
  pi[base+0] = gb + i0; pi[base+1] = gb + i1; pi[base+2] = gb + i2;
}

// ---------------- merge chunks -> idx + normalized weights ----------------
__global__ void k_nn_merge(const float* __restrict__ pd, const int* __restrict__ pi,
                           int* __restrict__ idx3, float* __restrict__ w3){
  int gid = blockIdx.x * 256 + threadIdx.x; // b*NQ + n
  int b = gid >> 13, n = gid & (NQ-1);
  float d0 = 3.4e38f, d1 = 3.4e38f, d2 = 3.4e38f;
  int i0 = 0, i1 = 0, i2 = 0;
  for (int ch = 0; ch < CHUNKS; ++ch){
    size_t base = (((size_t)b*CHUNKS + ch)*NQ + n)*3;
    #pragma unroll
    for (int k = 0; k < 3; ++k){
      float d = pd[base + k]; int gm = pi[base + k];
      bool c0 = d < d0, c1 = d < d1, c2 = d < d2;
      d2 = c1 ? d1 : (c2 ? d : d2);  i2 = c1 ? i1 : (c2 ? gm : i2);
      d1 = c0 ? d0 : (c1 ? d : d1);  i1 = c0 ? i0 : (c1 ? gm : i1);
      d0 = c0 ? d : d0;              i0 = c0 ? gm : i0;
    }
  }
  float w0 = 1.f / fmaxf(d0, 1e-10f);
  float w1 = 1.f / fmaxf(d1, 1e-10f);
  float w2 = 1.f / fmaxf(d2, 1e-10f);
  float s = w0 + w1 + w2;
  idx3[gid*3+0] = i0; idx3[gid*3+1] = i1; idx3[gid*3+2] = i2;
  w3[gid*3+0] = w0/s; w3[gid*3+1] = w1/s; w3[gid*3+2] = w2/s;
}

// ---------------- fused1 v2: skip-GEMM (K=128) + COALESCED row-gather merge ----------------
__global__ __launch_bounds__(256) void k_fused1(const unsigned short* __restrict__ W1b,
    const float* __restrict__ fu, const int* __restrict__ idx3, const float* __restrict__ w3,
    const unsigned short* __restrict__ Z,
    unsigned short* __restrict__ Y1, float* __restrict__ Sp, float* __restrict__ SSp){
  __shared__ unsigned short Yl[64*264];   // phase1 front aliased as Xl[64][136]
  int tile = blockIdx.x;          // 0..1023
  int b = tile & 7;               // XCD-locality for Z
  int n0 = (tile >> 3) << 6;
  int t = threadIdx.x;
  int l = t & 63, wv = t >> 6;
  int lr = l & 15, lg = l >> 4;
  int ob = wv << 6;
  // ---- stage fu ----
  {
    unsigned short (*Xl)[136] = (unsigned short(*)[136])Yl;
    int n = t & 63, cs0 = t >> 6;
    for (int it = 0; it < 32; ++it){
      int cs = cs0 + (it << 2);
      Xl[n][cs] = f2bf(fu[((size_t)b*CSK + cs)*NQ + n0 + n]);
    }
  }
  __syncthreads();
  // ---- skip-GEMM K=128 ----
  f32x4 acc[4][4];
  #pragma unroll
  for (int i = 0; i < 4; ++i)
    #pragma unroll
    for (int j = 0; j < 4; ++j)
      acc[i][j] = (f32x4){0.f, 0.f, 0.f, 0.f};
  {
    unsigned short (*Xl)[136] = (unsigned short(*)[136])Yl;
    #pragma unroll 1
    for (int kt = 0; kt < 4; ++kt){
      int k0 = (kt << 5) + (lg << 3);
      bf16x8 af[4], bv[4];
      #pragma unroll
      for (int of = 0; of < 4; ++of)
        af[of] = *(const bf16x8*)(W1b + (size_t)(ob + (of<<4) + lr)*CIN + 256 + k0); // skip cols
      #pragma unroll
      for (int nf = 0; nf < 4; ++nf)
        bv[nf] = *(const bf16x8*)&Xl[(nf<<4) + lr][k0];
      #pragma unroll
      for (int of = 0; of < 4; ++of)
        #pragma unroll
        for (int nf = 0; nf < 4; ++nf)
          acc[of][nf] = __builtin_amdgcn_mfma_f32_16x16x32_bf16(af[of], bv[nf], acc[of][nf], 0, 0, 0);
    }
  }
  __syncthreads(); // Xl dead
  // ---- GEMM partial -> LDS bf16 ----
  #pragma unroll
  for (int of = 0; of < 4; ++of){
    int o = ob + (of<<4) + (lg<<2);
    #pragma unroll
    for (int nf = 0; nf < 4; ++nf){
      int nl = (nf<<4) + lr;
      ushort4 pk;
      pk.x = f2bf(acc[of][nf][0]);
      pk.y = f2bf(acc[of][nf][1]);
      pk.z = f2bf(acc[of][nf][2]);
      pk.w = f2bf(acc[of][nf][3]);
      *(ushort4*)&Yl[nl*264 + o] = pk;
    }
  }
  __syncthreads();
  // ---- coalesced gather-merge + stats ----
  int hw = t >> 5;        // half-wave 0..7
  int c  = t & 31;        // lane within half-wave: channels 8c..8c+7
  float sv8[8], sq8[8];
  #pragma unroll
  for (int j = 0; j < 8; ++j){ sv8[j] = 0.f; sq8[j] = 0.f; }
  const unsigned short* Zb = Z + (((size_t)b*MP) << 8);
  #pragma unroll 2
  for (int i = 0; i < 8; ++i){
    int ql = (hw << 3) + i;
    int n = n0 + ql;
    int q = ((b << 13) + n) * 3;
    int j0 = idx3[q], j1 = idx3[q+1], j2 = idx3[q+2];
    float w0 = w3[q], w1 = w3[q+1], w2 = w3[q+2];
    ushort8 z0 = *(const ushort8*)(Zb + ((size_t)j0 << 8) + (c << 3));
    ushort8 z1 = *(const ushort8*)(Zb + ((size_t)j1 << 8) + (c << 3));
    ushort8 z2 = *(const ushort8*)(Zb + ((size_t)j2 << 8) + (c << 3));
    ushort8 cur = *(const ushort8*)&Yl[ql*264 + (c << 3)];
    ushort8 pk;
    #pragma unroll
    for (int j = 0; j < 8; ++j){
      float y = bf2f(cur[j]) + w0*bf2f(z0[j]) + w1*bf2f(z1[j]) + w2*bf2f(z2[j]);
      sv8[j] += y;
      sq8[j] += y*y;
      pk[j] = f2bf(y);
    }
    *(ushort8*)(Y1 + ((((size_t)b << 13) + n))*COUT + (c << 3)) = pk;
  }
  // combine the two half-waves of each wave, then write per-wave partials
  #pragma unroll
  for (int j = 0; j < 8; ++j){
    sv8[j] += __shfl_xor(sv8[j], 32);
    sq8[j] += __shfl_xor(sq8[j], 32);
  }
  if (l < 32){
    size_t row = (size_t)(tile*4 + wv)*256 + (c << 3);
    #pragma unroll
    for (int j = 0; j < 8; ++j){
      Sp[row + j] = sv8[j];
      SSp[row + j] = sq8[j];
    }
  }
}

// ---------------- reduce nt tile-partials -> BN scale/shift directly ----------------
__global__ __launch_bounds__(256) void k_reduce2(const float* __restrict__ Sp, const float* __restrict__ SSp,
    const float* __restrict__ g, const float* __restrict__ be,
    float* __restrict__ scale, float* __restrict__ shift, int nt){
  int t = threadIdx.x;
  int o = blockIdx.x * 4 + (t >> 6);   // channel 0..255
  int lane = t & 63;
  float s = 0.f, ss = 0.f;
  int jmax = nt >> 6;
  for (int j = 0; j < jmax; ++j){
    size_t row = (size_t)(lane + (j << 6))*256 + o;
    s += Sp[row]; ss += SSp[row];
  }
  #pragma unroll
  for (int off = 1; off < 64; off <<= 1){
    s += __shfl_xor(s, off); ss += __shfl_xor(ss, off);
  }
  if (lane == 0){
    float mean = s / 65536.f;
    float var = ss / 65536.f - mean*mean;
    float inv = rsqrtf(var + 1e-5f);
    float sc = g[o] * inv;
    scale[o] = sc;
    shift[o] = be[o] - mean * sc;
  }
}

// ---------------- GEMM2 v2: 32-query tiles, 2048 blocks, XCD batch mapping ----------------
__global__ __launch_bounds__(256) void k_gemm2(const unsigned short* __restrict__ W2b,
    const unsigned short* __restrict__ Y1, const float* __restrict__ scale1,
    const float* __restrict__ shift1, unsigned short* __restrict__ Y2,
    float* __restrict__ Sp, float* __restrict__ SSp){
  __shared__ unsigned short buf[256*36]; // phase1: Xl[32][264] (8448 < 9216); phase2: T[256][36]
  int tile = blockIdx.x;          // 0..2047
  int b = tile & 7;               // XCD-locality for Y1 slab
  int n0 = (tile >> 3) << 5;
  int t = threadIdx.x;
  {
    int nn0 = t >> 6;
    int cb = (t & 63) << 2;
    float scl[4], shl[4];
    #pragma unroll
    for (int j = 0; j < 4; ++j){ scl[j] = scale1[cb+j]; shl[j] = shift1[cb+j]; }
    for (int it = 0; it < 8; ++it){
      int nn = nn0 + (it << 2);
      size_t pos = ((size_t)b << 13) + n0 + nn;
      ushort4 a = *(const ushort4*)(Y1 + pos*COUT + cb);
      ushort4 r;
      r.x = f2bf(fmaxf(bf2f(a.x)*scl[0] + shl[0], 0.f));
      r.y = f2bf(fmaxf(bf2f(a.y)*scl[1] + shl[1], 0.f));
      r.z = f2bf(fmaxf(bf2f(a.z)*scl[2] + shl[2], 0.f));
      r.w = f2bf(fmaxf(bf2f(a.w)*scl[3] + shl[3], 0.f));
      *(ushort4*)&buf[nn*264 + cb] = r;
    }
  }
  __syncthreads();
  int l = t & 63, wv = t >> 6;
  int lr = l & 15, lg = l >> 4;
  int ob = wv << 6;
  f32x4 acc[4][2];
  #pragma unroll
  for (int i = 0; i < 4; ++i)
    #pragma unroll
    for (int j = 0; j < 2; ++j)
      acc[i][j] = (f32x4){0.f, 0.f, 0.f, 0.f};
  #pragma unroll 1
  for (int kt = 0; kt < 8; ++kt){
    int k0 = (kt << 5) + (lg << 3);
    bf16x8 af[4], bv[2];
    #pragma unroll
    for (int of = 0; of < 4; ++of)
      af[of] = *(const bf16x8*)(W2b + (size_t)(ob + (of<<4) + lr)*COUT + k0);
    #pragma unroll
    for (int nf = 0; nf < 2; ++nf)
      bv[nf] = *(const bf16x8*)&buf[((nf<<4) + lr)*264 + k0];
    #pragma unroll
    for (int of = 0; of < 4; ++of)
      #pragma unroll
      for (int nf = 0; nf < 2; ++nf)
        acc[of][nf] = __builtin_amdgcn_mfma_f32_16x16x32_bf16(af[of], bv[nf], acc[of][nf], 0, 0, 0);
  }
  // stats (pre-rounding, fp32)
  #pragma unroll
  for (int of = 0; of < 4; ++of){
    #pragma unroll
    for (int r = 0; r < 4; ++r){
      float sv = acc[of][0][r] + acc[of][1][r];
      float sq = acc[of][0][r]*acc[of][0][r] + acc[of][1][r]*acc[of][1][r];
      #pragma unroll
      for (int off = 1; off < 16; off <<= 1){
        sv += __shfl_xor(sv, off);
        sq += __shfl_xor(sq, off);
      }
      if (lr == 0){
        int o = ob + (of<<4) + (lg<<2) + r;
        Sp[(size_t)tile*256 + o] = sv;
        SSp[(size_t)tile*256 + o] = sq;
      }
    }
  }
  __syncthreads(); // all LDS reads done -> safe to overwrite as T
  #pragma unroll
  for (int of = 0; of < 4; ++of){
    int o = ob + (of<<4) + (lg<<2);
    #pragma unroll
    for (int nf = 0; nf < 2; ++nf){
      int n = (nf<<4) + lr;
      #pragma unroll
      for (int r = 0; r < 4; ++r)
        buf[(o + r)*36 + n] = f2bf(acc[of][nf][r]);
    }
  }
  __syncthreads();
  {
    int nx = (t & 15) << 1;
    int og = t >> 4;
    for (int it = 0; it < 16; ++it){
      int o = og + (it << 4);
      unsigned int v = (unsigned int)buf[o*36 + nx] | ((unsigned int)buf[o*36 + nx + 1] << 16);
      *(unsigned int*)(Y2 + (((size_t)b*COUT + o) << 13) + n0 + nx) = v;
    }
  }
}

// ---------------- final BN+ReLU -> fp32 out ----------------
__global__ void k_out(const unsigned short* __restrict__ Y2,
                      const float* __restrict__ scale2, const float* __restrict__ shift2,
                      float* __restrict__ out){
  size_t i = (size_t)blockIdx.x * 256 + threadIdx.x;
  size_t e = i << 2;
  int o = (int)((e >> 13) & 255);
  ushort4 v = *(const ushort4*)(Y2 + e);
  float sc = scale2[o], sh = shift2[o];
  float4 r;
  r.x = fmaxf(bf2f(v.x)*sc + sh, 0.f);
  r.y = fmaxf(bf2f(v.y)*sc + sh, 0.f);
  r.z = fmaxf(bf2f(v.z)*sc + sh, 0.f);
  r.w = fmaxf(bf2f(v.w)*sc + sh, 0.f);
  *(float4*)(out + e) = r;
}

extern "C" void kernel_launch(void* const* d_in, const int* in_sizes, int n_in,
                              void* d_out, int out_size, void* d_ws, size_t ws_size,
                              hipStream_t stream) {
  (void)in_sizes; (void)n_in; (void)out_size; (void)ws_size;
  const float* xu = (const float*)d_in[0];
  const float* xd = (const float*)d_in[1];
  const float* fu = (const float*)d_in[2];
  const float* fd = (const float*)d_in[3];
  const float* W1 = (const float*)d_in[4];
  const float* g1 = (const float*)d_in[5];
  const float* b1 = (const float*)d_in[6];
  const float* W2 = (const float*)d_in[7];
  const float* g2 = (const float*)d_in[8];
  const float* b2 = (const float*)d_in[9];
  float* out = (float*)d_out;

  char* w = (char*)d_ws;
  size_t off = 0;
  unsigned short* Z   = (unsigned short*)(w + off); off += (size_t)NB*MP*256*2;      // 8 MB
  unsigned short* W1b = (unsigned short*)(w + off); off += (size_t)COUT*CIN*2;
  unsigned short* W2b = (unsigned short*)(w + off); off += (size_t)COUT*COUT*2;
  float* pd  = (float*)(w + off); off += (size_t)NB*CHUNKS*NQ*3*4;
  int*   pi  = (int*)(w + off);   off += (size_t)NB*CHUNKS*NQ*3*4;
  int*   idx3= (int*)(w + off);   off += (size_t)NB*NQ*3*4;
  float* w3  = (float*)(w + off); off += (size_t)NB*NQ*3*4;
  unsigned short* Y1 = (unsigned short*)(w + off); off += (size_t)NB*NQ*COUT*2;      // 32 MB
  unsigned short* Y2 = (unsigned short*)(w + off); off += (size_t)NB*NQ*COUT*2;      // 32 MB
  float* Sp1  = (float*)(w + off); off += (size_t)4096*256*4;                        // 4 MB
  float* SSp1 = (float*)(w + off); off += (size_t)4096*256*4;
  float* Sp2  = (float*)(w + off); off += (size_t)2048*256*4;                        // 2 MB
  float* SSp2 = (float*)(w + off); off += (size_t)2048*256*4;
  float* scale1 = (float*)(w + off); off += 256*4;
  float* shift1 = (float*)(w + off); off += 256*4;
  float* scale2 = (float*)(w + off); off += 256*4;
  float* shift2 = (float*)(w + off); off += 256*4;

  k_cvt_w<<<dim3(384), dim3(256), 0, stream>>>(W1, W2, W1b, W2b);
  k_z<<<dim3(32, 8), dim3(256), 0, stream>>>(W1b, fd, Z);
  k_nn_part<<<dim3(32, CHUNKS, 8), dim3(256), 0, stream>>>(xu, xd, pd, pi);
  k_nn_merge<<<dim3(256), dim3(256), 0, stream>>>(pd, pi, idx3, w3);
  k_fused1<<<dim3(1024), dim3(256), 0, stream>>>(W1b, fu, idx3, w3, Z, Y1, Sp1, SSp1);
  k_reduce2<<<dim3(64), dim3(256), 0, stream>>>(Sp1, SSp1, g1, b1, scale1, shift1, 4096);
  k_gemm2<<<dim3(2048), dim3(256), 0, stream>>>(W2b, Y1, scale1, shift1, Y2, Sp2, SSp2);
  k_reduce2<<<dim3(64), dim3(256), 0, stream>>>(Sp2, SSp2, g2, b2, scale2, shift2, 2048);
  k_out<<<dim3(16384), dim3(256), 0, stream>>>(Y2, scale2, shift2, out);
}

// Round 19
// 179.685 us; speedup vs baseline: 1.0922x; 1.0922x over previous
//
#include <hip/hip_runtime.h>
#include <hip/hip_bf16.h>

#define NB 8
#define NQ 8192
#define MP 2048
#define CDW 256
#define CSK 128
#define CIN 384
#define COUT 256

typedef __bf16 bf16_t;
typedef bf16_t bf16x8 __attribute__((ext_vector_type(8)));
typedef float f32x4 __attribute__((ext_vector_type(4)));
typedef unsigned short ushort8 __attribute__((ext_vector_type(8)));

static __device__ __forceinline__ float bf2f(unsigned short u){
  union { unsigned int ui; float f; } v; v.ui = ((unsigned int)u) << 16; return v.f;
}
static __device__ __forceinline__ unsigned short f2bf(float f){
  union { float f; unsigned int u; } v; v.f = f;
  unsigned int u = v.u;
  return (unsigned short)((u + 0x7FFFu + ((u >> 16) & 1u)) >> 16);
}

// ---------------- weight conversion ----------------
__global__ void k_cvt_w(const float* __restrict__ W1, const float* __restrict__ W2,
                        unsigned short* __restrict__ W1b, unsigned short* __restrict__ W2b){
  int i = blockIdx.x * 256 + threadIdx.x;
  if (i < COUT*CIN) W1b[i] = f2bf(W1[i]);
  if (i < COUT*COUT) W2b[i] = f2bf(W2[i]);
}

// ---------------- Z = W1a * features_down : (B, M, 256) bf16, o-contiguous ----------------
__global__ __launch_bounds__(256) void k_z(const unsigned short* __restrict__ W1b,
    const float* __restrict__ fd, unsigned short* __restrict__ Z){
  __shared__ unsigned short Bl[64][264]; // [m][c], pad 8
  int b = blockIdx.y, m0 = blockIdx.x << 6;
  int t = threadIdx.x;
  {
    int m = t & 63, cs0 = t >> 6;
    for (int it = 0; it < 64; ++it){
      int c = cs0 + (it << 2);
      Bl[m][c] = f2bf(fd[((size_t)b*CDW + c)*MP + m0 + m]);
    }
  }
  __syncthreads();
  int l = t & 63, wv = t >> 6;
  int lr = l & 15, lg = l >> 4;
  int ob = wv << 6;
  f32x4 acc[4][4];
  #pragma unroll
  for (int i = 0; i < 4; ++i)
    #pragma unroll
    for (int j = 0; j < 4; ++j)
      acc[i][j] = (f32x4){0.f, 0.f, 0.f, 0.f};
  #pragma unroll 1
  for (int kt = 0; kt < 8; ++kt){
    int k0 = (kt << 5) + (lg << 3);
    bf16x8 af[4], bv[4];
    #pragma unroll
    for (int of = 0; of < 4; ++of)
      af[of] = *(const bf16x8*)(W1b + (size_t)(ob + (of<<4) + lr)*CIN + k0); // cols 0..255
    #pragma unroll
    for (int nf = 0; nf < 4; ++nf)
      bv[nf] = *(const bf16x8*)&Bl[(nf<<4) + lr][k0];
    #pragma unroll
    for (int of = 0; of < 4; ++of)
      #pragma unroll
      for (int nf = 0; nf < 4; ++nf)
        acc[of][nf] = __builtin_amdgcn_mfma_f32_16x16x32_bf16(af[of], bv[nf], acc[of][nf], 0, 0, 0);
  }
  #pragma unroll
  for (int of = 0; of < 4; ++of){
    int o = ob + (of<<4) + (lg<<2);
    #pragma unroll
    for (int nf = 0; nf < 4; ++nf){
      int m = m0 + (nf<<4) + lr;
      ushort4 pk;
      pk.x = f2bf(acc[of][nf][0]);
      pk.y = f2bf(acc[of][nf][1]);
      pk.z = f2bf(acc[of][nf][2]);
      pk.w = f2bf(acc[of][nf][3]);
      *(ushort4*)(Z + (((size_t)b*MP + m) << 8) + o) = pk;
    }
  }
}

// ---------------- 3-NN partial (M chunked, 512-pt chunks: skip x occupancy sweet spot) ----------------
#define CHUNKS 4
#define MC (MP/CHUNKS)

#define NN_SKIP(P)                                                           \
  asm volatile(                                                              \
      "v_fma_f32 %[s], %[qx], %[px], %[pw]\n\t"                              \
      "v_fma_f32 %[s], %[qy], %[py], %[s]\n\t"                               \
      "v_fma_f32 %[s], %[qz], %[pz], %[s]\n\t"                               \
      "v_cmp_gt_f32 vcc, %[s], %[s2]\n\t"                                    \
      "s_cbranch_vccz L_%=\n\t"                                              \
      "v_cmp_gt_f32 %[m1], %[s], %[s1]\n\t"                                  \
      "v_cmp_gt_f32 %[m0], %[s], %[s0]\n\t"                                  \
      "v_cndmask_b32 %[s2], %[s2], %[s], vcc\n\t"                            \
      "v_cndmask_b32 %[i2], %[i2], %[mi], vcc\n\t"                           \
      "v_cndmask_b32 %[s2], %[s2], %[s1], %[m1]\n\t"                         \
      "v_cndmask_b32 %[i2], %[i2], %[i1], %[m1]\n\t"                         \
      "v_cndmask_b32 %[s1], %[s1], %[s], %[m1]\n\t"                          \
      "v_cndmask_b32 %[i1], %[i1], %[mi], %[m1]\n\t"                         \
      "v_cndmask_b32 %[s1], %[s1], %[s0], %[m0]\n\t"                         \
      "v_cndmask_b32 %[i1], %[i1], %[i0], %[m0]\n\t"                         \
      "v_cndmask_b32 %[s0], %[s0], %[s], %[m0]\n\t"                          \
      "v_cndmask_b32 %[i0], %[i0], %[mi], %[m0]\n\t"                         \
      "L_%=:\n\t"                                                            \
      "v_add_u32 %[mi], 1, %[mi]\n\t"                                        \
      : [s]"=&v"(sv), [m0]"=&s"(mk0), [m1]"=&s"(mk1),                        \
        [s0]"+v"(s0), [s1]"+v"(s1), [s2]"+v"(s2),                            \
        [i0]"+v"(i0), [i1]"+v"(i1), [i2]"+v"(i2), [mi]"+v"(mi)               \
      : [qx]"v"(qx), [qy]"v"(qy), [qz]"v"(qz),                               \
        [px]"v"((P).x), [py]"v"((P).y), [pz]"v"((P).z), [pw]"v"((P).w)       \
      : "vcc")

__global__ __launch_bounds__(256, 2) void k_nn_part(const float* __restrict__ xu, const float* __restrict__ xd,
                                                    float* __restrict__ pd, int* __restrict__ pi){
  int b = blockIdx.z, ch = blockIdx.y, nt = blockIdx.x;
  int t = threadIdx.x;
  __shared__ float4 pts[MC];
  const float* xdb = xd + ((size_t)b*MP + (size_t)ch*MC)*3;
  for (int p = t; p < MC; p += 256){
    float x = xdb[p*3+0], y = xdb[p*3+1], z = xdb[p*3+2];
    pts[p] = make_float4(x, y, z, -0.5f*(x*x + y*y + z*z));
  }
  __syncthreads();
  int n = nt*256 + t;
  const float* q = xu + ((size_t)b*NQ + n)*3;
  float qx = q[0], qy = q[1], qz = q[2];
  float qs = qx*qx + qy*qy + qz*qz;
  float s0 = -3.4e38f, s1 = -3.4e38f, s2 = -3.4e38f;
  int i0 = 0, i1 = 0, i2 = 0, mi = 0;
  float sv;
  unsigned long long mk0, mk1;
  #pragma unroll 1
  for (int mb = 0; mb < MC; mb += 8){
    float4 P0 = pts[mb+0], P1 = pts[mb+1], P2 = pts[mb+2], P3 = pts[mb+3];
    float4 P4 = pts[mb+4], P5 = pts[mb+5], P6 = pts[mb+6], P7 = pts[mb+7];
    NN_SKIP(P0); NN_SKIP(P1); NN_SKIP(P2); NN_SKIP(P3);
    NN_SKIP(P4); NN_SKIP(P5); NN_SKIP(P6); NN_SKIP(P7);
  }
  int gb = ch*MC;
  size_t base = (((size_t)b*CHUNKS + ch)*NQ + n)*3;
  pd[base+0] = qs - 2.f*s0; pd[base+1] = qs - 2.f*s1; pd[base+2] = qs - 2.f*s2;
  pi[base+0] = gb + i0; pi[base+1] = gb + i1; pi[base+2] = gb + i2;
}

// ---------------- merge chunks -> idx + normalized weights ----------------
__global__ void k_nn_merge(const float* __restrict__ pd, const int* __restrict__ pi,
                           int* __restrict__ idx3, float* __restrict__ w3){
  int gid = blockIdx.x * 256 + threadIdx.x; // b*NQ + n
  int b = gid >> 13, n = gid & (NQ-1);
  float d0 = 3.4e38f, d1 = 3.4e38f, d2 = 3.4e38f;
  int i0 = 0, i1 = 0, i2 = 0;
  for (int ch = 0; ch < CHUNKS; ++ch){
    size_t base = (((size_t)b*CHUNKS + ch)*NQ + n)*3;
    #pragma unroll
    for (int k = 0; k < 3; ++k){
      float d = pd[base + k]; int gm = pi[base + k];
      bool c0 = d < d0, c1 = d < d1, c2 = d < d2;
      d2 = c1 ? d1 : (c2 ? d : d2);  i2 = c1 ? i1 : (c2 ? gm : i2);
      d1 = c0 ? d0 : (c1 ? d : d1);  i1 = c0 ? i0 : (c1 ? gm : i1);
      d0 = c0 ? d : d0;              i0 = c0 ? gm : i0;
    }
  }
  float w0 = 1.f / fmaxf(d0, 1e-10f);
  float w1 = 1.f / fmaxf(d1, 1e-10f);
  float w2 = 1.f / fmaxf(d2, 1e-10f);
  float s = w0 + w1 + w2;
  idx3[gid*3+0] = i0; idx3[gid*3+1] = i1; idx3[gid*3+2] = i2;
  w3[gid*3+0] = w0/s; w3[gid*3+1] = w1/s; w3[gid*3+2] = w2/s;
}

// ---------------- fused1 v2: skip-GEMM (K=128) + COALESCED row-gather merge ----------------
__global__ __launch_bounds__(256) void k_fused1(const unsigned short* __restrict__ W1b,
    const float* __restrict__ fu, const int* __restrict__ idx3, const float* __restrict__ w3,
    const unsigned short* __restrict__ Z,
    unsigned short* __restrict__ Y1, float* __restrict__ Sp, float* __restrict__ SSp){
  __shared__ unsigned short Yl[64*264];   // phase1 front aliased as Xl[64][136]
  int tile = blockIdx.x;          // 0..1023
  int b = tile & 7;               // XCD-locality for Z
  int n0 = (tile >> 3) << 6;
  int t = threadIdx.x;
  int l = t & 63, wv = t >> 6;
  int lr = l & 15, lg = l >> 4;
  int ob = wv << 6;
  // ---- stage fu ----
  {
    unsigned short (*Xl)[136] = (unsigned short(*)[136])Yl;
    int n = t & 63, cs0 = t >> 6;
    for (int it = 0; it < 32; ++it){
      int cs = cs0 + (it << 2);
      Xl[n][cs] = f2bf(fu[((size_t)b*CSK + cs)*NQ + n0 + n]);
    }
  }
  __syncthreads();
  // ---- skip-GEMM K=128 ----
  f32x4 acc[4][4];
  #pragma unroll
  for (int i = 0; i < 4; ++i)
    #pragma unroll
    for (int j = 0; j < 4; ++j)
      acc[i][j] = (f32x4){0.f, 0.f, 0.f, 0.f};
  {
    unsigned short (*Xl)[136] = (unsigned short(*)[136])Yl;
    #pragma unroll 1
    for (int kt = 0; kt < 4; ++kt){
      int k0 = (kt << 5) + (lg << 3);
      bf16x8 af[4], bv[4];
      #pragma unroll
      for (int of = 0; of < 4; ++of)
        af[of] = *(const bf16x8*)(W1b + (size_t)(ob + (of<<4) + lr)*CIN + 256 + k0); // skip cols
      #pragma unroll
      for (int nf = 0; nf < 4; ++nf)
        bv[nf] = *(const bf16x8*)&Xl[(nf<<4) + lr][k0];
      #pragma unroll
      for (int of = 0; of < 4; ++of)
        #pragma unroll
        for (int nf = 0; nf < 4; ++nf)
          acc[of][nf] = __builtin_amdgcn_mfma_f32_16x16x32_bf16(af[of], bv[nf], acc[of][nf], 0, 0, 0);
    }
  }
  __syncthreads(); // Xl dead
  // ---- GEMM partial -> LDS bf16 ----
  #pragma unroll
  for (int of = 0; of < 4; ++of){
    int o = ob + (of<<4) + (lg<<2);
    #pragma unroll
    for (int nf = 0; nf < 4; ++nf){
      int nl = (nf<<4) + lr;
      ushort4 pk;
      pk.x = f2bf(acc[of][nf][0]);
      pk.y = f2bf(acc[of][nf][1]);
      pk.z = f2bf(acc[of][nf][2]);
      pk.w = f2bf(acc[of][nf][3]);
      *(ushort4*)&Yl[nl*264 + o] = pk;
    }
  }
  __syncthreads();
  // ---- coalesced gather-merge + stats ----
  int hw = t >> 5;        // half-wave 0..7
  int c  = t & 31;        // lane within half-wave: channels 8c..8c+7
  float sv8[8], sq8[8];
  #pragma unroll
  for (int j = 0; j < 8; ++j){ sv8[j] = 0.f; sq8[j] = 0.f; }
  const unsigned short* Zb = Z + (((size_t)b*MP) << 8);
  #pragma unroll 2
  for (int i = 0; i < 8; ++i){
    int ql = (hw << 3) + i;
    int n = n0 + ql;
    int q = ((b << 13) + n) * 3;
    int j0 = idx3[q], j1 = idx3[q+1], j2 = idx3[q+2];
    float w0 = w3[q], w1 = w3[q+1], w2 = w3[q+2];
    ushort8 z0 = *(const ushort8*)(Zb + ((size_t)j0 << 8) + (c << 3));
    ushort8 z1 = *(const ushort8*)(Zb + ((size_t)j1 << 8) + (c << 3));
    ushort8 z2 = *(const ushort8*)(Zb + ((size_t)j2 << 8) + (c << 3));
    ushort8 cur = *(const ushort8*)&Yl[ql*264 + (c << 3)];
    ushort8 pk;
    #pragma unroll
    for (int j = 0; j < 8; ++j){
      float y = bf2f(cur[j]) + w0*bf2f(z0[j]) + w1*bf2f(z1[j]) + w2*bf2f(z2[j]);
      sv8[j] += y;
      sq8[j] += y*y;
      pk[j] = f2bf(y);
    }
    *(ushort8*)(Y1 + ((((size_t)b << 13) + n))*COUT + (c << 3)) = pk;
  }
  // combine the two half-waves of each wave, then write per-wave partials
  #pragma unroll
  for (int j = 0; j < 8; ++j){
    sv8[j] += __shfl_xor(sv8[j], 32);
    sq8[j] += __shfl_xor(sq8[j], 32);
  }
  if (l < 32){
    size_t row = (size_t)(tile*4 + wv)*256 + (c << 3);
    #pragma unroll
    for (int j = 0; j < 8; ++j){
      Sp[row + j] = sv8[j];
      SSp[row + j] = sq8[j];
    }
  }
}

// ---------------- reduce nt tile-partials -> BN scale/shift directly ----------------
__global__ __launch_bounds__(256) void k_reduce2(const float* __restrict__ Sp, const float* __restrict__ SSp,
    const float* __restrict__ g, const float* __restrict__ be,
    float* __restrict__ scale, float* __restrict__ shift, int nt){
  int t = threadIdx.x;
  int o = blockIdx.x * 4 + (t >> 6);   // channel 0..255
  int lane = t & 63;
  float s = 0.f, ss = 0.f;
  int jmax = nt >> 6;
  for (int j = 0; j < jmax; ++j){
    size_t row = (size_t)(lane + (j << 6))*256 + o;
    s += Sp[row]; ss += SSp[row];
  }
  #pragma unroll
  for (int off = 1; off < 64; off <<= 1){
    s += __shfl_xor(s, off); ss += __shfl_xor(ss, off);
  }
  if (lane == 0){
    float mean = s / 65536.f;
    float var = ss / 65536.f - mean*mean;
    float inv = rsqrtf(var + 1e-5f);
    float sc = g[o] * inv;
    scale[o] = sc;
    shift[o] = be[o] - mean * sc;
  }
}

// ---------------- GEMM2 (R17 config): 64-query tiles, 1024 blocks; ushort8 staging ----------------
__global__ __launch_bounds__(256) void k_gemm2(const unsigned short* __restrict__ W2b,
    const unsigned short* __restrict__ Y1, const float* __restrict__ scale1,
    const float* __restrict__ shift1, unsigned short* __restrict__ Y2,
    float* __restrict__ Sp, float* __restrict__ SSp){
  __shared__ unsigned short buf[256*68]; // phase1: Xl[64][264]; phase2: T[256][68]
  int tile = blockIdx.x;
  int b = tile >> 7;
  int n0 = (tile & 127) << 6;
  int t = threadIdx.x;
  {
    int nn0 = t >> 5;               // 8 rows per iter, 8 iters
    int cb = (t & 31) << 3;         // 8-channel slab
    float scl[8], shl[8];
    #pragma unroll
    for (int j = 0; j < 8; ++j){ scl[j] = scale1[cb+j]; shl[j] = shift1[cb+j]; }
    for (int it = 0; it < 8; ++it){
      int nn = nn0 + (it << 3);
      size_t pos = ((size_t)b << 13) + n0 + nn;
      ushort8 a = *(const ushort8*)(Y1 + pos*COUT + cb);
      ushort8 r;
      #pragma unroll
      for (int j = 0; j < 8; ++j)
        r[j] = f2bf(fmaxf(bf2f(a[j])*scl[j] + shl[j], 0.f));
      *(ushort8*)&buf[nn*264 + cb] = r;
    }
  }
  __syncthreads();
  int l = t & 63, wv = t >> 6;
  int lr = l & 15, lg = l >> 4;
  int ob = wv << 6;
  f32x4 acc[4][4];
  #pragma unroll
  for (int i = 0; i < 4; ++i)
    #pragma unroll
    for (int j = 0; j < 4; ++j)
      acc[i][j] = (f32x4){0.f, 0.f, 0.f, 0.f};
  #pragma unroll 1
  for (int kt = 0; kt < 8; ++kt){
    int k0 = (kt << 5) + (lg << 3);
    bf16x8 af[4], bv[4];
    #pragma unroll
    for (int of = 0; of < 4; ++of)
      af[of] = *(const bf16x8*)(W2b + (size_t)(ob + (of<<4) + lr)*COUT + k0);
    #pragma unroll
    for (int nf = 0; nf < 4; ++nf)
      bv[nf] = *(const bf16x8*)&buf[((nf<<4) + lr)*264 + k0];
    #pragma unroll
    for (int of = 0; of < 4; ++of)
      #pragma unroll
      for (int nf = 0; nf < 4; ++nf)
        acc[of][nf] = __builtin_amdgcn_mfma_f32_16x16x32_bf16(af[of], bv[nf], acc[of][nf], 0, 0, 0);
  }
  // stats (pre-rounding, fp32)
  #pragma unroll
  for (int of = 0; of < 4; ++of){
    #pragma unroll
    for (int r = 0; r < 4; ++r){
      float sv = acc[of][0][r] + acc[of][1][r] + acc[of][2][r] + acc[of][3][r];
      float sq = acc[of][0][r]*acc[of][0][r] + acc[of][1][r]*acc[of][1][r]
               + acc[of][2][r]*acc[of][2][r] + acc[of][3][r]*acc[of][3][r];
      #pragma unroll
      for (int off = 1; off < 16; off <<= 1){
        sv += __shfl_xor(sv, off);
        sq += __shfl_xor(sq, off);
      }
      if (lr == 0){
        int o = ob + (of<<4) + (lg<<2) + r;
        Sp[(size_t)tile*256 + o] = sv;
        SSp[(size_t)tile*256 + o] = sq;
      }
    }
  }
  __syncthreads(); // all LDS reads done -> safe to overwrite as T
  #pragma unroll
  for (int of = 0; of < 4; ++of){
    int o = ob + (of<<4) + (lg<<2);
    #pragma unroll
    for (int nf = 0; nf < 4; ++nf){
      int n = (nf<<4) + lr;
      #pragma unroll
      for (int r = 0; r < 4; ++r)
        buf[(o + r)*68 + n] = f2bf(acc[of][nf][r]);
    }
  }
  __syncthreads();
  {
    int nx = (t & 31) << 1;
    int og = t >> 5;
    for (int it = 0; it < 32; ++it){
      int o = og + (it << 3);
      unsigned int v = (unsigned int)buf[o*68 + nx] | ((unsigned int)buf[o*68 + nx + 1] << 16);
      *(unsigned int*)(Y2 + (((size_t)b*COUT + o) << 13) + n0 + nx) = v;
    }
  }
}

// ---------------- final BN+ReLU -> fp32 out ----------------
__global__ void k_out(const unsigned short* __restrict__ Y2,
                      const float* __restrict__ scale2, const float* __restrict__ shift2,
                      float* __restrict__ out){
  size_t i = (size_t)blockIdx.x * 256 + threadIdx.x;
  size_t e = i << 2;
  int o = (int)((e >> 13) & 255);
  ushort4 v = *(const ushort4*)(Y2 + e);
  float sc = scale2[o], sh = shift2[o];
  float4 r;
  r.x = fmaxf(bf2f(v.x)*sc + sh, 0.f);
  r.y = fmaxf(bf2f(v.y)*sc + sh, 0.f);
  r.z = fmaxf(bf2f(v.z)*sc + sh, 0.f);
  r.w = fmaxf(bf2f(v.w)*sc + sh, 0.f);
  *(float4*)(out + e) = r;
}

extern "C" void kernel_launch(void* const* d_in, const int* in_sizes, int n_in,
                              void* d_out, int out_size, void* d_ws, size_t ws_size,
                              hipStream_t stream) {
  (void)in_sizes; (void)n_in; (void)out_size; (void)ws_size;
  const float* xu = (const float*)d_in[0];
  const float* xd = (const float*)d_in[1];
  const float* fu = (const float*)d_in[2];
  const float* fd = (const float*)d_in[3];
  const float* W1 = (const float*)d_in[4];
  const float* g1 = (const float*)d_in[5];
  const float* b1 = (const float*)d_in[6];
  const float* W2 = (const float*)d_in[7];
  const float* g2 = (const float*)d_in[8];
  const float* b2 = (const float*)d_in[9];
  float* out = (float*)d_out;

  char* w = (char*)d_ws;
  size_t off = 0;
  unsigned short* Z   = (unsigned short*)(w + off); off += (size_t)NB*MP*256*2;      // 8 MB
  unsigned short* W1b = (unsigned short*)(w + off); off += (size_t)COUT*CIN*2;
  unsigned short* W2b = (unsigned short*)(w + off); off += (size_t)COUT*COUT*2;
  float* pd  = (float*)(w + off); off += (size_t)NB*CHUNKS*NQ*3*4;
  int*   pi  = (int*)(w + off);   off += (size_t)NB*CHUNKS*NQ*3*4;
  int*   idx3= (int*)(w + off);   off += (size_t)NB*NQ*3*4;
  float* w3  = (float*)(w + off); off += (size_t)NB*NQ*3*4;
  unsigned short* Y1 = (unsigned short*)(w + off); off += (size_t)NB*NQ*COUT*2;      // 32 MB
  unsigned short* Y2 = (unsigned short*)(w + off); off += (size_t)NB*NQ*COUT*2;      // 32 MB
  float* Sp1  = (float*)(w + off); off += (size_t)4096*256*4;                        // 4 MB
  float* SSp1 = (float*)(w + off); off += (size_t)4096*256*4;
  float* Sp2  = (float*)(w + off); off += (size_t)1024*256*4;
  float* SSp2 = (float*)(w + off); off += (size_t)1024*256*4;
  float* scale1 = (float*)(w + off); off += 256*4;
  float* shift1 = (float*)(w + off); off += 256*4;
  float* scale2 = (float*)(w + off); off += 256*4;
  float* shift2 = (float*)(w + off); off += 256*4;

  k_cvt_w<<<dim3(384), dim3(256), 0, stream>>>(W1, W2, W1b, W2b);
  k_z<<<dim3(32, 8), dim3(256), 0, stream>>>(W1b, fd, Z);
  k_nn_part<<<dim3(32, CHUNKS, 8), dim3(256), 0, stream>>>(xu, xd, pd, pi);
  k_nn_merge<<<dim3(256), dim3(256), 0, stream>>>(pd, pi, idx3, w3);
  k_fused1<<<dim3(1024), dim3(256), 0, stream>>>(W1b, fu, idx3, w3, Z, Y1, Sp1, SSp1);
  k_reduce2<<<dim3(64), dim3(256), 0, stream>>>(Sp1, SSp1, g1, b1, scale1, shift1, 4096);
  k_gemm2<<<dim3(1024), dim3(256), 0, stream>>>(W2b, Y1, scale1, shift1, Y2, Sp2, SSp2);
  k_reduce2<<<dim3(64), dim3(256), 0, stream>>>(Sp2, SSp2, g2, b2, scale2, shift2, 1024);
  k_out<<<dim3(16384), dim3(256), 0, stream>>>(Y2, scale2, shift2, out);
}